// Round 4
// baseline (1748.600 us; speedup 1.0000x reference)
//
#include <hip/hip_runtime.h>
#include <hip/hip_bf16.h>
#include <cstdint>

// Problem constants (B=4, L=2048, D=1024, E=8, K=2, H=HS=4096)
#define T_TOKENS 8192
#define DMODEL   1024
#define DHID     4096
#define NEXP     8

typedef float  f32x4  __attribute__((ext_vector_type(4)));
typedef __bf16 bf16x8 __attribute__((ext_vector_type(8)));

__device__ __forceinline__ void async_copy16(const void* gp, void* lp) {
    __builtin_amdgcn_global_load_lds(
        (const __attribute__((address_space(1))) void*)gp,
        (__attribute__((address_space(3))) void*)lp, 16, 0, 0);
}

__device__ __forceinline__ float gelu_tanh(float x) {
    // tanh-gelu via sigmoid identity: 0.5x(1+tanh(u)) = x * sigmoid(2u)
    // 2u = x*(1.59576912 + 0.07135481*x^2);  ~8 VALU ops vs ~25 for tanhf.
    float z = x * (1.5957691216057308f + 0.07135481283247289f * x * x);
    return x / (1.0f + __expf(-z));
}

// ---------------------------------------------------------------------------
// Transpose + fp32->bf16 convert: src (batch, R, C) row-major -> dst (batch, C, R)
// block (32,8), grid (C/32, R/32, batch)
// ---------------------------------------------------------------------------
__global__ void transpose_cvt(const float* __restrict__ src,
                              __hip_bfloat16* __restrict__ dst, int R, int C) {
    __shared__ float tile[32][33];
    int bz = blockIdx.z;
    const float* s = src + (size_t)bz * R * C;
    __hip_bfloat16* d = dst + (size_t)bz * R * C;
    int c0 = blockIdx.x * 32, r0 = blockIdx.y * 32;
    int tx = threadIdx.x, ty = threadIdx.y;
#pragma unroll
    for (int i = 0; i < 4; i++) {
        int r = r0 + ty + i * 8;
        tile[ty + i * 8][tx] = s[(size_t)r * C + c0 + tx];
    }
    __syncthreads();
#pragma unroll
    for (int i = 0; i < 4; i++) {
        int c = c0 + ty + i * 8;
        d[(size_t)c * R + r0 + tx] = __float2bfloat16(tile[tx][ty + i * 8]);
    }
}

// ---------------------------------------------------------------------------
// cond = silu(time_c) @ ada_w + ada_b   (B=4 rows, 2048 cols each)
// ---------------------------------------------------------------------------
__global__ void cond_kernel(const float* __restrict__ time_c,
                            const float* __restrict__ ada_w,
                            const float* __restrict__ ada_b,
                            float* __restrict__ cond) {
    __shared__ float sl[DMODEL];
    int b = blockIdx.x >> 3;
    int j = ((blockIdx.x & 7) << 8) + threadIdx.x;   // 0..2047
    for (int i = threadIdx.x; i < DMODEL; i += 256) {
        float tc = time_c[b * DMODEL + i];
        sl[i] = tc / (1.0f + __expf(-tc));
    }
    __syncthreads();
    float acc = ada_b[j];
    for (int i = 0; i < DMODEL; i++)
        acc += sl[i] * ada_w[(size_t)i * 2048 + j];
    cond[b * 2048 + j] = acc;
}

// ---------------------------------------------------------------------------
// Fused LayerNorm + adaptive modulation + bf16 cast + router (softmax top-2)
// one block (256 thr) per token
// ---------------------------------------------------------------------------
__global__ __launch_bounds__(256) void ln_gate_kernel(
    const float* __restrict__ x, const float* __restrict__ cond,
    const float* __restrict__ gate_w,
    __hip_bfloat16* __restrict__ xnb,
    int* __restrict__ topi, float* __restrict__ topw, int* __restrict__ counts) {
    int t = blockIdx.x;
    int b = t >> 11;                      // L = 2048
    int tid = threadIdx.x, lane = tid & 63, wave = tid >> 6;
    const float4* xr = (const float4*)(x + (size_t)t * DMODEL);
    float4 v = xr[tid];
    float s = v.x + v.y + v.z + v.w;
    float q = v.x * v.x + v.y * v.y + v.z * v.z + v.w * v.w;
#pragma unroll
    for (int o = 32; o > 0; o >>= 1) {
        s += __shfl_down(s, o, 64);
        q += __shfl_down(q, o, 64);
    }
    __shared__ float red[8];
    if (lane == 0) { red[wave] = s; red[4 + wave] = q; }
    __syncthreads();
    float tsum = red[0] + red[1] + red[2] + red[3];
    float tsq  = red[4] + red[5] + red[6] + red[7];
    float mu   = tsum * (1.0f / DMODEL);
    float var  = tsq * (1.0f / DMODEL) - mu * mu;
    float rstd = rsqrtf(var + 1e-6f);

    int j = tid * 4;
    const float4* cb = (const float4*)(cond + (size_t)b * 2048);
    float4 sh = cb[tid];        // shift = cond[:, :1024]
    float4 sc = cb[256 + tid];  // scale = cond[:, 1024:]
    float xv[4];
    xv[0] = (v.x - mu) * rstd * (1.0f + sc.x) + sh.x;
    xv[1] = (v.y - mu) * rstd * (1.0f + sc.y) + sh.y;
    xv[2] = (v.z - mu) * rstd * (1.0f + sc.z) + sh.z;
    xv[3] = (v.w - mu) * rstd * (1.0f + sc.w) + sh.w;
    union { ushort4 u4; __hip_bfloat16 h[4]; } pk;
#pragma unroll
    for (int r = 0; r < 4; r++) pk.h[r] = __float2bfloat16(xv[r]);
    *((ushort4*)(xnb + (size_t)t * DMODEL + j)) = pk.u4;

    // router logits: xn . gate_w[:, e], gate_w (1024, 8) row-major
    float g[8] = {0, 0, 0, 0, 0, 0, 0, 0};
    const float4* gw = (const float4*)gate_w;
#pragma unroll
    for (int r = 0; r < 4; r++) {
        float4 ga = gw[(j + r) * 2];
        float4 gb = gw[(j + r) * 2 + 1];
        g[0] += xv[r] * ga.x; g[1] += xv[r] * ga.y;
        g[2] += xv[r] * ga.z; g[3] += xv[r] * ga.w;
        g[4] += xv[r] * gb.x; g[5] += xv[r] * gb.y;
        g[6] += xv[r] * gb.z; g[7] += xv[r] * gb.w;
    }
#pragma unroll
    for (int e = 0; e < 8; e++) {
#pragma unroll
        for (int o = 32; o > 0; o >>= 1) g[e] += __shfl_down(g[e], o, 64);
    }
    __shared__ float gred[4][8];
    if (lane == 0) {
#pragma unroll
        for (int e = 0; e < 8; e++) gred[wave][e] = g[e];
    }
    __syncthreads();
    if (tid == 0) {
        float l[8];
#pragma unroll
        for (int e = 0; e < 8; e++)
            l[e] = gred[0][e] + gred[1][e] + gred[2][e] + gred[3][e];
        // top-2 (ties -> lower index, matches lax.top_k)
        int i0 = 0; float v0 = l[0];
        int i1 = -1; float v1 = -3.4e38f;
        for (int e = 1; e < 8; e++) {
            if (l[e] > v0) { v1 = v0; i1 = i0; v0 = l[e]; i0 = e; }
            else if (l[e] > v1) { v1 = l[e]; i1 = e; }
        }
        // renormalized top-2 softmax weights: w0 = 1/(1+exp(l1-l0))
        float r = __expf(v1 - v0);
        float w0 = 1.0f / (1.0f + r);
        topi[2 * t] = i0; topi[2 * t + 1] = i1;
        topw[2 * t] = w0; topw[2 * t + 1] = 1.0f - w0;
        atomicAdd(&counts[i0], 1);
        atomicAdd(&counts[i1], 1);
    }
}

__global__ void scan_kernel(const int* __restrict__ counts,
                            int* __restrict__ offs, int* __restrict__ cursors) {
    if (threadIdx.x == 0) {
        int a = 0;
        for (int e = 0; e < NEXP; e++) { offs[e] = a; cursors[e] = a; a += counts[e]; }
    }
}

// fill_kernel: also records slots[2t+k] = position of (t,k) in the permuted
// order, so the routed-down result can be gathered WITHOUT atomics.
__global__ void fill_kernel(const int* __restrict__ topi, const float* __restrict__ topw,
                            int* __restrict__ cursors,
                            int* __restrict__ rowlist, float* __restrict__ wlist,
                            int* __restrict__ slots) {
    int t = blockIdx.x * 256 + threadIdx.x;   // 0..8191
#pragma unroll
    for (int k = 0; k < 2; k++) {
        int e = topi[2 * t + k];
        int pos = atomicAdd(&cursors[e], 1);
        rowlist[pos] = t;
        wlist[pos] = topw[2 * t + k];
        slots[2 * t + k] = pos;
    }
}

// combine: out[t] += yr[slot0(t)] + yr[slot1(t)]  (weights pre-applied in MODE 3)
// one block (256 thr * float4 = 1024 cols) per token
__global__ __launch_bounds__(256) void combine_kernel(
    const int* __restrict__ slots, const float* __restrict__ yr,
    float* __restrict__ out) {
    int t = blockIdx.x;
    int p0 = slots[2 * t], p1 = slots[2 * t + 1];
    int i = threadIdx.x;
    const float4* a = (const float4*)(yr + (size_t)p0 * DMODEL);
    const float4* b = (const float4*)(yr + (size_t)p1 * DMODEL);
    float4* o = (float4*)(out + (size_t)t * DMODEL);
    float4 va = a[i], vb = b[i], vo = o[i];
    vo.x += va.x + vb.x;
    vo.y += va.y + vb.y;
    vo.z += va.z + vb.z;
    vo.w += va.w + vb.w;
    o[i] = vo;
}

// ---------------------------------------------------------------------------
// bf16 GEMM, C = A(MxK) * Bt(NxK)^T  — 128x128 tile, BK=64, 4 waves 2x2,
// 16x16x32 MFMA, global_load_lds width-16 staging.
// 2-PHASE double-buffered k-loop (T3-minimum, m248v2 recipe): stage tile t+1
// into buf^1 BEFORE computing tile t from buf[cur]; one explicit vmcnt(0)
// drain + one __syncthreads per K-step, landing AFTER the MFMAs so the
// global-load latency hides under compute.  Race-free:
//   - stage targets the buffer nobody reads this step;
//   - all reads of the buffer being overwritten completed before the
//     previous barrier;
//   - the drain+barrier guarantees tile t+1 fully landed (each wave drains
//     its own loads; all waves stage disjoint chunks).
// LDS layout is XOR-swizzled: row r's k-chunk kc (8 elems, 16B) lives at
// byte offset r*128 + ((kc ^ (r&7))<<4) within the active buffer.
// MODE 0: shared up:   A=xnb dense, epi gelu(v+sb1) -> hs bf16
// MODE 1: shared down: A=hs dense,  epi out = x + v + sb2 (fp32)
// MODE 2: routed up:   A=xnb gathered via rowlist, epi gelu(v+b1[e]) -> hr bf16
// MODE 3: routed down: A=hr dense-in-segment, epi yr[pos] = w*(v+b2[e]) (fp32,
//         dense coalesced store, NO atomics — combine_kernel scatters later)
// LDS = 64 KB/block -> max 2 blocks/CU; __launch_bounds__(256,2) matches.
// ---------------------------------------------------------------------------
template <int MODE>
__global__ __launch_bounds__(256, 2) void gemm_bt(
    const __hip_bfloat16* __restrict__ A,
    const __hip_bfloat16* __restrict__ Bt,
    const float* __restrict__ bias,
    const float* __restrict__ xres,
    float* __restrict__ outf,
    __hip_bfloat16* __restrict__ outb,
    const int* __restrict__ rowlist,
    const float* __restrict__ wlist,
    const int* __restrict__ offs,
    const int* __restrict__ counts,
    int K, int N) {
    int e = 0, seg_off = 0, Mcnt = 0;
    if constexpr (MODE >= 2) {
        e = blockIdx.z;
        Mcnt = counts[e];
        if ((int)blockIdx.x * 128 >= Mcnt) return;   // ragged early-exit (block-uniform)
        seg_off = offs[e];
    }
    const __hip_bfloat16* Bte = Bt + (size_t)e * (size_t)N * K;
    const float* biase = bias + (size_t)e * N;
    int row0 = blockIdx.x * 128, col0 = blockIdx.y * 128;

    // double-buffered tiles: [2][128 rows][64 k] bf16 = 2 x 16 KB each (64 KB total)
    __shared__ __align__(16) __hip_bfloat16 sA[2][128 * 64];
    __shared__ __align__(16) __hip_bfloat16 sB[2][128 * 64];

    int tid = threadIdx.x, wave = tid >> 6, lane = tid & 63;
    int wm = wave >> 1, wn = wave & 1;

    // staging pointers: chunk c = wave*4+i covers 8 rows (A) / 8 n-rows (B);
    // lane L -> row c*8 + L/8, k-chunk (L%8) ^ (L/8)  [XOR swizzle]
    int kc = ((lane & 7) ^ (lane >> 3)) * 8;   // swizzled k-element offset
    const __hip_bfloat16* aptr[4];
    const __hip_bfloat16* bptr[4];
#pragma unroll
    for (int i = 0; i < 4; i++) {
        int c = wave * 4 + i;
        int rr = c * 8 + (lane >> 3);
        size_t arow;
        if constexpr (MODE == 0 || MODE == 1) {
            arow = (size_t)(row0 + rr);
        } else {
            int p = row0 + rr; if (p > Mcnt - 1) p = Mcnt - 1;   // clamp ragged tail
            arow = (MODE == 2) ? (size_t)rowlist[seg_off + p] : (size_t)(seg_off + p);
        }
        aptr[i] = A + arow * K + kc;
        int nn = col0 + c * 8 + (lane >> 3);
        bptr[i] = Bte + (size_t)nn * K + kc;
    }

    f32x4 acc[4][4];
#pragma unroll
    for (int tm = 0; tm < 4; tm++)
#pragma unroll
        for (int tn = 0; tn < 4; tn++) acc[tm][tn] = (f32x4){0.f, 0.f, 0.f, 0.f};

    char* sAc = (char*)&sA[0][0];
    char* sBc = (char*)&sB[0][0];

    int nt = K >> 6;
    // prologue: stage tile 0 into buf 0
#pragma unroll
    for (int i = 0; i < 4; i++) {
        int c = wave * 4 + i;
        async_copy16(aptr[i], sAc + c * 1024);
        async_copy16(bptr[i], sBc + c * 1024);
        aptr[i] += 64;
        bptr[i] += 64;
    }
    asm volatile("s_waitcnt vmcnt(0)" ::: "memory");
    __syncthreads();   // tile 0 landed for all waves

    int cur = 0;
    for (int t = 0; t < nt; ++t) {
        if (t + 1 < nt) {
            // issue next-tile loads into the OTHER buffer (latency hides under MFMA)
            char* dA = (char*)&sA[cur ^ 1][0];
            char* dB = (char*)&sB[cur ^ 1][0];
#pragma unroll
            for (int i = 0; i < 4; i++) {
                int c = wave * 4 + i;
                async_copy16(aptr[i], dA + c * 1024);
                async_copy16(bptr[i], dB + c * 1024);
                aptr[i] += 64;
                bptr[i] += 64;
            }
        }
        const short* sa = (const short*)&sA[cur][0];
        const short* sb = (const short*)&sB[cur][0];
#pragma unroll
        for (int kk = 0; kk < 64; kk += 32) {
            // k-chunk index for this lane-half, then XOR with row&7 (== lane&7
            // for all fragment rows, since fragment row = multiple-of-16 + (lane&15))
            int kbc = (kk >> 3) + (lane >> 4);
            int swz = ((kbc ^ (lane & 7)) << 3);   // short offset within row
            bf16x8 af[4], bfr[4];
#pragma unroll
            for (int tm = 0; tm < 4; tm++)
                af[tm] = *(const bf16x8*)(sa + (size_t)(wm * 64 + tm * 16 + (lane & 15)) * 64 + swz);
#pragma unroll
            for (int tn = 0; tn < 4; tn++)
                bfr[tn] = *(const bf16x8*)(sb + (size_t)(wn * 64 + tn * 16 + (lane & 15)) * 64 + swz);
#pragma unroll
            for (int tm = 0; tm < 4; tm++)
#pragma unroll
                for (int tn = 0; tn < 4; tn++)
                    acc[tm][tn] = __builtin_amdgcn_mfma_f32_16x16x32_bf16(
                        af[tm], bfr[tn], acc[tm][tn], 0, 0, 0);
        }
        if (t + 1 < nt) {
            asm volatile("s_waitcnt vmcnt(0)" ::: "memory");   // stage(t+1) landed
            __syncthreads();                                   // all reads of buf[cur] done
        }
        cur ^= 1;
    }

    // epilogue — C/D layout: col = lane&15, row = (lane>>4)*4 + i
#pragma unroll
    for (int tm = 0; tm < 4; tm++) {
        int rbase = wm * 64 + tm * 16 + ((lane >> 4) << 2);
        float wv[4];
        if constexpr (MODE == 3) {
#pragma unroll
            for (int i = 0; i < 4; i++) {
                int p = row0 + rbase + i;
                wv[i] = (p < Mcnt) ? wlist[seg_off + p] : 0.0f;
            }
        }
#pragma unroll
        for (int tn = 0; tn < 4; tn++) {
            int c = col0 + wn * 64 + tn * 16 + (lane & 15);
            float bb = biase[c];
#pragma unroll
            for (int i = 0; i < 4; i++) {
                int rl = rbase + i;
                float v = acc[tm][tn][i] + bb;
                if constexpr (MODE == 0) {
                    outb[(size_t)(row0 + rl) * N + c] = __float2bfloat16(gelu_tanh(v));
                } else if constexpr (MODE == 1) {
                    size_t idx = (size_t)(row0 + rl) * N + c;
                    outf[idx] = xres[idx] + v;
                } else if constexpr (MODE == 2) {
                    int p = row0 + rl;
                    if (p < Mcnt)
                        outb[(size_t)(seg_off + p) * N + c] = __float2bfloat16(gelu_tanh(v));
                } else {
                    int p = row0 + rl;
                    if (p < Mcnt)
                        outf[(size_t)(seg_off + p) * N + c] = wv[i] * v;
                }
            }
        }
    }
}

// ---------------------------------------------------------------------------
extern "C" void kernel_launch(void* const* d_in, const int* in_sizes, int n_in,
                              void* d_out, int out_size, void* d_ws, size_t ws_size,
                              hipStream_t stream) {
    const float* x      = (const float*)d_in[0];
    const float* time_c = (const float*)d_in[1];
    const float* ada_w  = (const float*)d_in[2];
    const float* ada_b  = (const float*)d_in[3];
    const float* gate_w = (const float*)d_in[4];
    const float* w1     = (const float*)d_in[5];
    const float* b1     = (const float*)d_in[6];
    const float* w2     = (const float*)d_in[7];
    const float* b2     = (const float*)d_in[8];
    const float* sw1    = (const float*)d_in[9];
    const float* sb1    = (const float*)d_in[10];
    const float* sw2    = (const float*)d_in[11];
    const float* sb2    = (const float*)d_in[12];
    float* out = (float*)d_out;
    (void)in_sizes; (void)n_in; (void)out_size; (void)ws_size;

    char* ws = (char*)d_ws;
    size_t off = 0;
    auto alloc = [&](size_t bytes) -> char* {
        char* p = ws + off;
        off += (bytes + 255) & ~(size_t)255;
        return p;
    };
    __hip_bfloat16* xnb  = (__hip_bfloat16*)alloc((size_t)T_TOKENS * DMODEL * 2);
    __hip_bfloat16* w1t  = (__hip_bfloat16*)alloc((size_t)NEXP * DMODEL * DHID * 2);
    __hip_bfloat16* w2t  = (__hip_bfloat16*)alloc((size_t)NEXP * DMODEL * DHID * 2);
    __hip_bfloat16* sw1t = (__hip_bfloat16*)alloc((size_t)DMODEL * DHID * 2);
    __hip_bfloat16* sw2t = (__hip_bfloat16*)alloc((size_t)DMODEL * DHID * 2);
    __hip_bfloat16* hs   = (__hip_bfloat16*)alloc((size_t)T_TOKENS * DHID * 2);
    __hip_bfloat16* hr   = (__hip_bfloat16*)alloc((size_t)2 * T_TOKENS * DHID * 2);
    float* cond    = (float*)alloc(4 * 2048 * 4);
    int*   topi    = (int*)alloc(T_TOKENS * 2 * 4);
    float* topw    = (float*)alloc(T_TOKENS * 2 * 4);
    int*   rowlist = (int*)alloc(2 * T_TOKENS * 4);
    float* wlist   = (float*)alloc(2 * T_TOKENS * 4);
    int*   slots   = (int*)alloc(2 * T_TOKENS * 4);
    int*   counts  = (int*)alloc(256);
    int*   offs    = (int*)alloc(256);
    int*   cursors = (int*)alloc(256);
    // yr (routed-down weighted contributions, fp32, 2T x D = 67.1 MB) aliases
    // hs (8192 x 4096 bf16 = 67.1 MB): hs is dead after gemm_bt<1>, and stream
    // ordering guarantees gemm_bt<1> completes before gemm_bt<3> writes yr.
    float* yr = (float*)hs;

    hipMemsetAsync(counts, 0, NEXP * sizeof(int), stream);

    // weight convert+transpose to bf16 NxK
    dim3 tb(32, 8);
    transpose_cvt<<<dim3(128, 32, 8), tb, 0, stream>>>(w1, w1t, 1024, 4096);
    transpose_cvt<<<dim3(32, 128, 8), tb, 0, stream>>>(w2, w2t, 4096, 1024);
    transpose_cvt<<<dim3(128, 32, 1), tb, 0, stream>>>(sw1, sw1t, 1024, 4096);
    transpose_cvt<<<dim3(32, 128, 1), tb, 0, stream>>>(sw2, sw2t, 4096, 1024);

    cond_kernel<<<32, 256, 0, stream>>>(time_c, ada_w, ada_b, cond);
    ln_gate_kernel<<<T_TOKENS, 256, 0, stream>>>(x, cond, gate_w, xnb, topi, topw, counts);
    scan_kernel<<<1, 64, 0, stream>>>(counts, offs, cursors);
    fill_kernel<<<32, 256, 0, stream>>>(topi, topw, cursors, rowlist, wlist, slots);

    // shared expert
    gemm_bt<0><<<dim3(64, 32), 256, 0, stream>>>(xnb, sw1t, sb1, nullptr, nullptr, hs,
                                                 nullptr, nullptr, nullptr, nullptr, 1024, 4096);
    gemm_bt<1><<<dim3(64, 8), 256, 0, stream>>>(hs, sw2t, sb2, x, out, nullptr,
                                                nullptr, nullptr, nullptr, nullptr, 4096, 1024);
    // routed experts (gathered up, dense-in-segment weighted down, no atomics)
    gemm_bt<2><<<dim3(64, 32, 8), 256, 0, stream>>>(xnb, w1t, b1, nullptr, nullptr, hr,
                                                    rowlist, nullptr, offs, counts, 1024, 4096);
    gemm_bt<3><<<dim3(64, 8, 8), 256, 0, stream>>>(hr, w2t, b2, nullptr, yr, nullptr,
                                                   nullptr, wlist, offs, counts, 4096, 1024);
    combine_kernel<<<T_TOKENS, 256, 0, stream>>>(slots, yr, out);
}

// Round 5
// 1382.077 us; speedup vs baseline: 1.2652x; 1.2652x over previous
//
#include <hip/hip_runtime.h>
#include <hip/hip_bf16.h>
#include <cstdint>

// Problem constants (B=4, L=2048, D=1024, E=8, K=2, H=HS=4096)
#define T_TOKENS 8192
#define DMODEL   1024
#define DHID     4096
#define NEXP     8

typedef float  f32x4  __attribute__((ext_vector_type(4)));
typedef __bf16 bf16x8 __attribute__((ext_vector_type(8)));

__device__ __forceinline__ void async_copy16(const void* gp, void* lp) {
    __builtin_amdgcn_global_load_lds(
        (const __attribute__((address_space(1))) void*)gp,
        (__attribute__((address_space(3))) void*)lp, 16, 0, 0);
}

__device__ __forceinline__ float gelu_tanh(float x) {
    // tanh-gelu via sigmoid identity: 0.5x(1+tanh(u)) = x * sigmoid(2u)
    // 2u = x*(1.59576912 + 0.07135481*x^2);  ~8 VALU ops vs ~25 for tanhf.
    float z = x * (1.5957691216057308f + 0.07135481283247289f * x * x);
    return x / (1.0f + __expf(-z));
}

// ---------------------------------------------------------------------------
// Transpose + fp32->bf16 convert: src (batch, R, C) row-major -> dst (batch, C, R)
// block (32,8), grid (C/32, R/32, batch)
// ---------------------------------------------------------------------------
__global__ void transpose_cvt(const float* __restrict__ src,
                              __hip_bfloat16* __restrict__ dst, int R, int C) {
    __shared__ float tile[32][33];
    int bz = blockIdx.z;
    const float* s = src + (size_t)bz * R * C;
    __hip_bfloat16* d = dst + (size_t)bz * R * C;
    int c0 = blockIdx.x * 32, r0 = blockIdx.y * 32;
    int tx = threadIdx.x, ty = threadIdx.y;
#pragma unroll
    for (int i = 0; i < 4; i++) {
        int r = r0 + ty + i * 8;
        tile[ty + i * 8][tx] = s[(size_t)r * C + c0 + tx];
    }
    __syncthreads();
#pragma unroll
    for (int i = 0; i < 4; i++) {
        int c = c0 + ty + i * 8;
        d[(size_t)c * R + r0 + tx] = __float2bfloat16(tile[tx][ty + i * 8]);
    }
}

// ---------------------------------------------------------------------------
// cond = silu(time_c) @ ada_w + ada_b   (B=4 rows, 2048 cols each)
// ---------------------------------------------------------------------------
__global__ void cond_kernel(const float* __restrict__ time_c,
                            const float* __restrict__ ada_w,
                            const float* __restrict__ ada_b,
                            float* __restrict__ cond) {
    __shared__ float sl[DMODEL];
    int b = blockIdx.x >> 3;
    int j = ((blockIdx.x & 7) << 8) + threadIdx.x;   // 0..2047
    for (int i = threadIdx.x; i < DMODEL; i += 256) {
        float tc = time_c[b * DMODEL + i];
        sl[i] = tc / (1.0f + __expf(-tc));
    }
    __syncthreads();
    float acc = ada_b[j];
    for (int i = 0; i < DMODEL; i++)
        acc += sl[i] * ada_w[(size_t)i * 2048 + j];
    cond[b * 2048 + j] = acc;
}

// ---------------------------------------------------------------------------
// Fused LayerNorm + adaptive modulation + bf16 cast + router (softmax top-2)
// one block (256 thr) per token
// ---------------------------------------------------------------------------
__global__ __launch_bounds__(256) void ln_gate_kernel(
    const float* __restrict__ x, const float* __restrict__ cond,
    const float* __restrict__ gate_w,
    __hip_bfloat16* __restrict__ xnb,
    int* __restrict__ topi, float* __restrict__ topw, int* __restrict__ counts) {
    int t = blockIdx.x;
    int b = t >> 11;                      // L = 2048
    int tid = threadIdx.x, lane = tid & 63, wave = tid >> 6;
    const float4* xr = (const float4*)(x + (size_t)t * DMODEL);
    float4 v = xr[tid];
    float s = v.x + v.y + v.z + v.w;
    float q = v.x * v.x + v.y * v.y + v.z * v.z + v.w * v.w;
#pragma unroll
    for (int o = 32; o > 0; o >>= 1) {
        s += __shfl_down(s, o, 64);
        q += __shfl_down(q, o, 64);
    }
    __shared__ float red[8];
    if (lane == 0) { red[wave] = s; red[4 + wave] = q; }
    __syncthreads();
    float tsum = red[0] + red[1] + red[2] + red[3];
    float tsq  = red[4] + red[5] + red[6] + red[7];
    float mu   = tsum * (1.0f / DMODEL);
    float var  = tsq * (1.0f / DMODEL) - mu * mu;
    float rstd = rsqrtf(var + 1e-6f);

    int j = tid * 4;
    const float4* cb = (const float4*)(cond + (size_t)b * 2048);
    float4 sh = cb[tid];        // shift = cond[:, :1024]
    float4 sc = cb[256 + tid];  // scale = cond[:, 1024:]
    float xv[4];
    xv[0] = (v.x - mu) * rstd * (1.0f + sc.x) + sh.x;
    xv[1] = (v.y - mu) * rstd * (1.0f + sc.y) + sh.y;
    xv[2] = (v.z - mu) * rstd * (1.0f + sc.z) + sh.z;
    xv[3] = (v.w - mu) * rstd * (1.0f + sc.w) + sh.w;
    union { ushort4 u4; __hip_bfloat16 h[4]; } pk;
#pragma unroll
    for (int r = 0; r < 4; r++) pk.h[r] = __float2bfloat16(xv[r]);
    *((ushort4*)(xnb + (size_t)t * DMODEL + j)) = pk.u4;

    // router logits: xn . gate_w[:, e], gate_w (1024, 8) row-major
    float g[8] = {0, 0, 0, 0, 0, 0, 0, 0};
    const float4* gw = (const float4*)gate_w;
#pragma unroll
    for (int r = 0; r < 4; r++) {
        float4 ga = gw[(j + r) * 2];
        float4 gb = gw[(j + r) * 2 + 1];
        g[0] += xv[r] * ga.x; g[1] += xv[r] * ga.y;
        g[2] += xv[r] * ga.z; g[3] += xv[r] * ga.w;
        g[4] += xv[r] * gb.x; g[5] += xv[r] * gb.y;
        g[6] += xv[r] * gb.z; g[7] += xv[r] * gb.w;
    }
#pragma unroll
    for (int e = 0; e < 8; e++) {
#pragma unroll
        for (int o = 32; o > 0; o >>= 1) g[e] += __shfl_down(g[e], o, 64);
    }
    __shared__ float gred[4][8];
    if (lane == 0) {
#pragma unroll
        for (int e = 0; e < 8; e++) gred[wave][e] = g[e];
    }
    __syncthreads();
    if (tid == 0) {
        float l[8];
#pragma unroll
        for (int e = 0; e < 8; e++)
            l[e] = gred[0][e] + gred[1][e] + gred[2][e] + gred[3][e];
        // top-2 (ties -> lower index, matches lax.top_k)
        int i0 = 0; float v0 = l[0];
        int i1 = -1; float v1 = -3.4e38f;
        for (int e = 1; e < 8; e++) {
            if (l[e] > v0) { v1 = v0; i1 = i0; v0 = l[e]; i0 = e; }
            else if (l[e] > v1) { v1 = l[e]; i1 = e; }
        }
        // renormalized top-2 softmax weights: w0 = 1/(1+exp(l1-l0))
        float r = __expf(v1 - v0);
        float w0 = 1.0f / (1.0f + r);
        topi[2 * t] = i0; topi[2 * t + 1] = i1;
        topw[2 * t] = w0; topw[2 * t + 1] = 1.0f - w0;
        atomicAdd(&counts[i0], 1);
        atomicAdd(&counts[i1], 1);
    }
}

__global__ void scan_kernel(const int* __restrict__ counts,
                            int* __restrict__ offs, int* __restrict__ cursors) {
    if (threadIdx.x == 0) {
        int a = 0;
        for (int e = 0; e < NEXP; e++) { offs[e] = a; cursors[e] = a; a += counts[e]; }
    }
}

// fill_kernel: also records slots[2t+k] = position of (t,k) in the permuted
// order, so the routed-down result can be gathered WITHOUT atomics.
__global__ void fill_kernel(const int* __restrict__ topi, const float* __restrict__ topw,
                            int* __restrict__ cursors,
                            int* __restrict__ rowlist, float* __restrict__ wlist,
                            int* __restrict__ slots) {
    int t = blockIdx.x * 256 + threadIdx.x;   // 0..8191
#pragma unroll
    for (int k = 0; k < 2; k++) {
        int e = topi[2 * t + k];
        int pos = atomicAdd(&cursors[e], 1);
        rowlist[pos] = t;
        wlist[pos] = topw[2 * t + k];
        slots[2 * t + k] = pos;
    }
}

// combine: out[t] += yr[slot0(t)] + yr[slot1(t)]  (weights pre-applied in MODE 3)
// one block (256 thr * float4 = 1024 cols) per token
__global__ __launch_bounds__(256) void combine_kernel(
    const int* __restrict__ slots, const float* __restrict__ yr,
    float* __restrict__ out) {
    int t = blockIdx.x;
    int p0 = slots[2 * t], p1 = slots[2 * t + 1];
    int i = threadIdx.x;
    const float4* a = (const float4*)(yr + (size_t)p0 * DMODEL);
    const float4* b = (const float4*)(yr + (size_t)p1 * DMODEL);
    float4* o = (float4*)(out + (size_t)t * DMODEL);
    float4 va = a[i], vb = b[i], vo = o[i];
    vo.x += va.x + vb.x;
    vo.y += va.y + vb.y;
    vo.z += va.z + vb.z;
    vo.w += va.w + vb.w;
    o[i] = vo;
}

// ---------------------------------------------------------------------------
// bf16 GEMM, C = A(MxK) * Bt(NxK)^T  — 128x128 tile, BK=64, 4 waves 2x2,
// 16x16x32 MFMA, global_load_lds width-16 staging.  REVERTED to the proven
// single-buffer serial k-loop: Round-4 measured the 64 KB double-buffer
// variant at 2 blocks/CU and it LOST (548 vs 408 us) — TLP from 4 blocks/CU
// outweighs 1-deep intra-block pipelining on this structure (matches
// m99/m100: explicit dbuf neutral/negative).
// LDS layout is XOR-swizzled: row r's k-chunk kc (8 elems, 16B) lives at
// byte offset r*128 + ((kc ^ (r&7))<<4).  Rows 0..7 of a 16-row fragment
// read then span all 32 banks (2-way alias rows 8..15 = free).
// MODE 0: shared up:   A=xnb dense, epi gelu(v+sb1) -> hs bf16
// MODE 1: shared down: A=hs dense,  epi out = x + v + sb2 (fp32)
// MODE 2: routed up:   A=xnb gathered via rowlist, epi gelu(v+b1[e]) -> hr bf16
// MODE 3: routed down: A=hr dense-in-segment, epi yr[pos] = w*(v+b2[e]) (fp32,
//         dense coalesced store, NO atomics — combine_kernel scatters later)
// ---------------------------------------------------------------------------
template <int MODE>
__global__ __launch_bounds__(256, 4) void gemm_bt(
    const __hip_bfloat16* __restrict__ A,
    const __hip_bfloat16* __restrict__ Bt,
    const float* __restrict__ bias,
    const float* __restrict__ xres,
    float* __restrict__ outf,
    __hip_bfloat16* __restrict__ outb,
    const int* __restrict__ rowlist,
    const float* __restrict__ wlist,
    const int* __restrict__ offs,
    const int* __restrict__ counts,
    int K, int N) {
    int e = 0, seg_off = 0, Mcnt = 0;
    if constexpr (MODE >= 2) {
        e = blockIdx.z;
        Mcnt = counts[e];
        if ((int)blockIdx.x * 128 >= Mcnt) return;   // ragged early-exit
        seg_off = offs[e];
    }
    const __hip_bfloat16* Bte = Bt + (size_t)e * (size_t)N * K;
    const float* biase = bias + (size_t)e * N;
    int row0 = blockIdx.x * 128, col0 = blockIdx.y * 128;

    __shared__ __align__(16) __hip_bfloat16 sA[128 * 64];
    __shared__ __align__(16) __hip_bfloat16 sB[128 * 64];

    int tid = threadIdx.x, wave = tid >> 6, lane = tid & 63;
    int wm = wave >> 1, wn = wave & 1;

    // staging pointers: chunk c = wave*4+i covers 8 rows (A) / 8 n-rows (B);
    // lane L -> row c*8 + L/8, k-chunk (L%8) ^ (L/8)  [XOR swizzle]
    int kc = ((lane & 7) ^ (lane >> 3)) * 8;   // swizzled k-element offset
    const __hip_bfloat16* aptr[4];
    const __hip_bfloat16* bptr[4];
#pragma unroll
    for (int i = 0; i < 4; i++) {
        int c = wave * 4 + i;
        int rr = c * 8 + (lane >> 3);
        size_t arow;
        if constexpr (MODE == 0 || MODE == 1) {
            arow = (size_t)(row0 + rr);
        } else {
            int p = row0 + rr; if (p > Mcnt - 1) p = Mcnt - 1;   // clamp ragged tail
            arow = (MODE == 2) ? (size_t)rowlist[seg_off + p] : (size_t)(seg_off + p);
        }
        aptr[i] = A + arow * K + kc;
        int nn = col0 + c * 8 + (lane >> 3);
        bptr[i] = Bte + (size_t)nn * K + kc;
    }

    f32x4 acc[4][4];
#pragma unroll
    for (int tm = 0; tm < 4; tm++)
#pragma unroll
        for (int tn = 0; tn < 4; tn++) acc[tm][tn] = (f32x4){0.f, 0.f, 0.f, 0.f};

    char* sAc = (char*)&sA[0];
    char* sBc = (char*)&sB[0];

    for (int k0 = 0; k0 < K; k0 += 64) {
#pragma unroll
        for (int i = 0; i < 4; i++) {
            int c = wave * 4 + i;
            async_copy16(aptr[i], sAc + c * 1024);
            async_copy16(bptr[i], sBc + c * 1024);
            aptr[i] += 64;
            bptr[i] += 64;
        }
        asm volatile("s_waitcnt vmcnt(0)" ::: "memory");
        __syncthreads();
        const short* sa = (const short*)sAc;
        const short* sb = (const short*)sBc;
#pragma unroll
        for (int kk = 0; kk < 64; kk += 32) {
            // k-chunk index for this lane-half, then XOR with row&7 (== lane&7
            // for all fragment rows, since fragment row = multiple-of-16 + (lane&15))
            int kbc = (kk >> 3) + (lane >> 4);
            int swz = ((kbc ^ (lane & 7)) << 3);   // short offset within row
            bf16x8 af[4], bfr[4];
#pragma unroll
            for (int tm = 0; tm < 4; tm++)
                af[tm] = *(const bf16x8*)(sa + (size_t)(wm * 64 + tm * 16 + (lane & 15)) * 64 + swz);
#pragma unroll
            for (int tn = 0; tn < 4; tn++)
                bfr[tn] = *(const bf16x8*)(sb + (size_t)(wn * 64 + tn * 16 + (lane & 15)) * 64 + swz);
#pragma unroll
            for (int tm = 0; tm < 4; tm++)
#pragma unroll
                for (int tn = 0; tn < 4; tn++)
                    acc[tm][tn] = __builtin_amdgcn_mfma_f32_16x16x32_bf16(
                        af[tm], bfr[tn], acc[tm][tn], 0, 0, 0);
        }
        __syncthreads();
    }

    // epilogue — C/D layout: col = lane&15, row = (lane>>4)*4 + i
#pragma unroll
    for (int tm = 0; tm < 4; tm++) {
        int rbase = wm * 64 + tm * 16 + ((lane >> 4) << 2);
        float wv[4];
        if constexpr (MODE == 3) {
#pragma unroll
            for (int i = 0; i < 4; i++) {
                int p = row0 + rbase + i;
                wv[i] = (p < Mcnt) ? wlist[seg_off + p] : 0.0f;
            }
        }
#pragma unroll
        for (int tn = 0; tn < 4; tn++) {
            int c = col0 + wn * 64 + tn * 16 + (lane & 15);
            float bb = biase[c];
#pragma unroll
            for (int i = 0; i < 4; i++) {
                int rl = rbase + i;
                float v = acc[tm][tn][i] + bb;
                if constexpr (MODE == 0) {
                    outb[(size_t)(row0 + rl) * N + c] = __float2bfloat16(gelu_tanh(v));
                } else if constexpr (MODE == 1) {
                    size_t idx = (size_t)(row0 + rl) * N + c;
                    outf[idx] = xres[idx] + v;
                } else if constexpr (MODE == 2) {
                    int p = row0 + rl;
                    if (p < Mcnt)
                        outb[(size_t)(seg_off + p) * N + c] = __float2bfloat16(gelu_tanh(v));
                } else {
                    int p = row0 + rl;
                    if (p < Mcnt)
                        outf[(size_t)(seg_off + p) * N + c] = wv[i] * v;
                }
            }
        }
    }
}

// ---------------------------------------------------------------------------
// Launch order is chosen for L3 producer->consumer adjacency: total workspace
// (~370 MB) exceeds the 256 MB Infinity Cache, so each weight transpose runs
// IMMEDIATELY before the GEMM that consumes it (w1t -> MODE2, w2t -> MODE3,
// sw1t -> MODE0, sw2t -> MODE1).  This keeps each GEMM's B-operand (67 MB)
// L3-resident at read time instead of HBM-cold after ~300 MB of traffic.
// ---------------------------------------------------------------------------
extern "C" void kernel_launch(void* const* d_in, const int* in_sizes, int n_in,
                              void* d_out, int out_size, void* d_ws, size_t ws_size,
                              hipStream_t stream) {
    const float* x      = (const float*)d_in[0];
    const float* time_c = (const float*)d_in[1];
    const float* ada_w  = (const float*)d_in[2];
    const float* ada_b  = (const float*)d_in[3];
    const float* gate_w = (const float*)d_in[4];
    const float* w1     = (const float*)d_in[5];
    const float* b1     = (const float*)d_in[6];
    const float* w2     = (const float*)d_in[7];
    const float* b2     = (const float*)d_in[8];
    const float* sw1    = (const float*)d_in[9];
    const float* sb1    = (const float*)d_in[10];
    const float* sw2    = (const float*)d_in[11];
    const float* sb2    = (const float*)d_in[12];
    float* out = (float*)d_out;
    (void)in_sizes; (void)n_in; (void)out_size; (void)ws_size;

    char* ws = (char*)d_ws;
    size_t off = 0;
    auto alloc = [&](size_t bytes) -> char* {
        char* p = ws + off;
        off += (bytes + 255) & ~(size_t)255;
        return p;
    };
    __hip_bfloat16* xnb  = (__hip_bfloat16*)alloc((size_t)T_TOKENS * DMODEL * 2);
    __hip_bfloat16* w1t  = (__hip_bfloat16*)alloc((size_t)NEXP * DMODEL * DHID * 2);
    __hip_bfloat16* w2t  = (__hip_bfloat16*)alloc((size_t)NEXP * DMODEL * DHID * 2);
    __hip_bfloat16* sw1t = (__hip_bfloat16*)alloc((size_t)DMODEL * DHID * 2);
    __hip_bfloat16* sw2t = (__hip_bfloat16*)alloc((size_t)DMODEL * DHID * 2);
    __hip_bfloat16* hs   = (__hip_bfloat16*)alloc((size_t)T_TOKENS * DHID * 2);
    __hip_bfloat16* hr   = (__hip_bfloat16*)alloc((size_t)2 * T_TOKENS * DHID * 2);
    float* cond    = (float*)alloc(4 * 2048 * 4);
    int*   topi    = (int*)alloc(T_TOKENS * 2 * 4);
    float* topw    = (float*)alloc(T_TOKENS * 2 * 4);
    int*   rowlist = (int*)alloc(2 * T_TOKENS * 4);
    float* wlist   = (float*)alloc(2 * T_TOKENS * 4);
    int*   slots   = (int*)alloc(2 * T_TOKENS * 4);
    int*   counts  = (int*)alloc(256);
    int*   offs    = (int*)alloc(256);
    int*   cursors = (int*)alloc(256);
    // yr (routed-down weighted contributions, fp32, 2T x D = 67.1 MB) aliases
    // hs (8192 x 4096 bf16 = 67.1 MB): hs is dead after gemm_bt<1>, and stream
    // ordering guarantees gemm_bt<1> completes before gemm_bt<3> writes yr.
    float* yr = (float*)hs;

    hipMemsetAsync(counts, 0, NEXP * sizeof(int), stream);

    dim3 tb(32, 8);

    // --- routing + normalization first (xnb / rowlist ready for all GEMMs) ---
    cond_kernel<<<32, 256, 0, stream>>>(time_c, ada_w, ada_b, cond);
    ln_gate_kernel<<<T_TOKENS, 256, 0, stream>>>(x, cond, gate_w, xnb, topi, topw, counts);
    scan_kernel<<<1, 64, 0, stream>>>(counts, offs, cursors);
    fill_kernel<<<32, 256, 0, stream>>>(topi, topw, cursors, rowlist, wlist, slots);

    // --- shared expert: transpose each weight right before its GEMM ---
    transpose_cvt<<<dim3(128, 32, 1), tb, 0, stream>>>(sw1, sw1t, 1024, 4096);
    gemm_bt<0><<<dim3(64, 32), 256, 0, stream>>>(xnb, sw1t, sb1, nullptr, nullptr, hs,
                                                 nullptr, nullptr, nullptr, nullptr, 1024, 4096);
    transpose_cvt<<<dim3(32, 128, 1), tb, 0, stream>>>(sw2, sw2t, 4096, 1024);
    gemm_bt<1><<<dim3(64, 8), 256, 0, stream>>>(hs, sw2t, sb2, x, out, nullptr,
                                                nullptr, nullptr, nullptr, nullptr, 4096, 1024);

    // --- routed experts: w1t hot for MODE2, w2t hot for MODE3 ---
    transpose_cvt<<<dim3(128, 32, 8), tb, 0, stream>>>(w1, w1t, 1024, 4096);
    gemm_bt<2><<<dim3(64, 32, 8), 256, 0, stream>>>(xnb, w1t, b1, nullptr, nullptr, hr,
                                                    rowlist, nullptr, offs, counts, 1024, 4096);
    transpose_cvt<<<dim3(32, 128, 8), tb, 0, stream>>>(w2, w2t, 4096, 1024);
    gemm_bt<3><<<dim3(64, 8, 8), 256, 0, stream>>>(hr, w2t, b2, nullptr, yr, nullptr,
                                                   nullptr, wlist, offs, counts, 4096, 1024);
    combine_kernel<<<T_TOKENS, 256, 0, stream>>>(slots, yr, out);
}

// Round 7
// 1289.698 us; speedup vs baseline: 1.3558x; 1.0716x over previous
//
#include <hip/hip_runtime.h>
#include <hip/hip_bf16.h>
#include <cstdint>

// Problem constants (B=4, L=2048, D=1024, E=8, K=2, H=HS=4096)
#define T_TOKENS 8192
#define DMODEL   1024
#define DHID     4096
#define NEXP     8

typedef float  f32x4  __attribute__((ext_vector_type(4)));
typedef __bf16 bf16x8 __attribute__((ext_vector_type(8)));

__device__ __forceinline__ void async_copy16(const void* gp, void* lp) {
    __builtin_amdgcn_global_load_lds(
        (const __attribute__((address_space(1))) void*)gp,
        (__attribute__((address_space(3))) void*)lp, 16, 0, 0);
}

__device__ __forceinline__ float gelu_tanh(float x) {
    // tanh-gelu via sigmoid identity: 0.5x(1+tanh(u)) = x * sigmoid(2u)
    // 2u = x*(1.59576912 + 0.07135481*x^2);  ~8 VALU ops vs ~25 for tanhf.
    float z = x * (1.5957691216057308f + 0.07135481283247289f * x * x);
    return x / (1.0f + __expf(-z));
}

// ---------------------------------------------------------------------------
// Transpose + fp32->bf16 convert: src (batch, R, C) row-major -> dst (batch, C, R)
// block (32,8), grid (C/32, R/32, batch)
// ---------------------------------------------------------------------------
__global__ void transpose_cvt(const float* __restrict__ src,
                              __hip_bfloat16* __restrict__ dst, int R, int C) {
    __shared__ float tile[32][33];
    int bz = blockIdx.z;
    const float* s = src + (size_t)bz * R * C;
    __hip_bfloat16* d = dst + (size_t)bz * R * C;
    int c0 = blockIdx.x * 32, r0 = blockIdx.y * 32;
    int tx = threadIdx.x, ty = threadIdx.y;
#pragma unroll
    for (int i = 0; i < 4; i++) {
        int r = r0 + ty + i * 8;
        tile[ty + i * 8][tx] = s[(size_t)r * C + c0 + tx];
    }
    __syncthreads();
#pragma unroll
    for (int i = 0; i < 4; i++) {
        int c = c0 + ty + i * 8;
        d[(size_t)c * R + r0 + tx] = __float2bfloat16(tile[tx][ty + i * 8]);
    }
}

// ---------------------------------------------------------------------------
// cond = silu(time_c) @ ada_w + ada_b   (B=4 rows, 2048 cols each)
// ---------------------------------------------------------------------------
__global__ void cond_kernel(const float* __restrict__ time_c,
                            const float* __restrict__ ada_w,
                            const float* __restrict__ ada_b,
                            float* __restrict__ cond) {
    __shared__ float sl[DMODEL];
    int b = blockIdx.x >> 3;
    int j = ((blockIdx.x & 7) << 8) + threadIdx.x;   // 0..2047
    for (int i = threadIdx.x; i < DMODEL; i += 256) {
        float tc = time_c[b * DMODEL + i];
        sl[i] = tc / (1.0f + __expf(-tc));
    }
    __syncthreads();
    float acc = ada_b[j];
    for (int i = 0; i < DMODEL; i++)
        acc += sl[i] * ada_w[(size_t)i * 2048 + j];
    cond[b * 2048 + j] = acc;
}

// ---------------------------------------------------------------------------
// Fused LayerNorm + adaptive modulation + bf16 cast + router (softmax top-2)
// one block (256 thr) per token
// ---------------------------------------------------------------------------
__global__ __launch_bounds__(256) void ln_gate_kernel(
    const float* __restrict__ x, const float* __restrict__ cond,
    const float* __restrict__ gate_w,
    __hip_bfloat16* __restrict__ xnb,
    int* __restrict__ topi, float* __restrict__ topw, int* __restrict__ counts) {
    int t = blockIdx.x;
    int b = t >> 11;                      // L = 2048
    int tid = threadIdx.x, lane = tid & 63, wave = tid >> 6;
    const float4* xr = (const float4*)(x + (size_t)t * DMODEL);
    float4 v = xr[tid];
    float s = v.x + v.y + v.z + v.w;
    float q = v.x * v.x + v.y * v.y + v.z * v.z + v.w * v.w;
#pragma unroll
    for (int o = 32; o > 0; o >>= 1) {
        s += __shfl_down(s, o, 64);
        q += __shfl_down(q, o, 64);
    }
    __shared__ float red[8];
    if (lane == 0) { red[wave] = s; red[4 + wave] = q; }
    __syncthreads();
    float tsum = red[0] + red[1] + red[2] + red[3];
    float tsq  = red[4] + red[5] + red[6] + red[7];
    float mu   = tsum * (1.0f / DMODEL);
    float var  = tsq * (1.0f / DMODEL) - mu * mu;
    float rstd = rsqrtf(var + 1e-6f);

    int j = tid * 4;
    const float4* cb = (const float4*)(cond + (size_t)b * 2048);
    float4 sh = cb[tid];        // shift = cond[:, :1024]
    float4 sc = cb[256 + tid];  // scale = cond[:, 1024:]
    float xv[4];
    xv[0] = (v.x - mu) * rstd * (1.0f + sc.x) + sh.x;
    xv[1] = (v.y - mu) * rstd * (1.0f + sc.y) + sh.y;
    xv[2] = (v.z - mu) * rstd * (1.0f + sc.z) + sh.z;
    xv[3] = (v.w - mu) * rstd * (1.0f + sc.w) + sh.w;
    union { ushort4 u4; __hip_bfloat16 h[4]; } pk;
#pragma unroll
    for (int r = 0; r < 4; r++) pk.h[r] = __float2bfloat16(xv[r]);
    *((ushort4*)(xnb + (size_t)t * DMODEL + j)) = pk.u4;

    // router logits: xn . gate_w[:, e], gate_w (1024, 8) row-major
    float g[8] = {0, 0, 0, 0, 0, 0, 0, 0};
    const float4* gw = (const float4*)gate_w;
#pragma unroll
    for (int r = 0; r < 4; r++) {
        float4 ga = gw[(j + r) * 2];
        float4 gb = gw[(j + r) * 2 + 1];
        g[0] += xv[r] * ga.x; g[1] += xv[r] * ga.y;
        g[2] += xv[r] * ga.z; g[3] += xv[r] * ga.w;
        g[4] += xv[r] * gb.x; g[5] += xv[r] * gb.y;
        g[6] += xv[r] * gb.z; g[7] += xv[r] * gb.w;
    }
#pragma unroll
    for (int e = 0; e < 8; e++) {
#pragma unroll
        for (int o = 32; o > 0; o >>= 1) g[e] += __shfl_down(g[e], o, 64);
    }
    __shared__ float gred[4][8];
    if (lane == 0) {
#pragma unroll
        for (int e = 0; e < 8; e++) gred[wave][e] = g[e];
    }
    __syncthreads();
    if (tid == 0) {
        float l[8];
#pragma unroll
        for (int e = 0; e < 8; e++)
            l[e] = gred[0][e] + gred[1][e] + gred[2][e] + gred[3][e];
        // top-2 (ties -> lower index, matches lax.top_k)
        int i0 = 0; float v0 = l[0];
        int i1 = -1; float v1 = -3.4e38f;
        for (int e = 1; e < 8; e++) {
            if (l[e] > v0) { v1 = v0; i1 = i0; v0 = l[e]; i0 = e; }
            else if (l[e] > v1) { v1 = l[e]; i1 = e; }
        }
        // renormalized top-2 softmax weights: w0 = 1/(1+exp(l1-l0))
        float r = __expf(v1 - v0);
        float w0 = 1.0f / (1.0f + r);
        topi[2 * t] = i0; topi[2 * t + 1] = i1;
        topw[2 * t] = w0; topw[2 * t + 1] = 1.0f - w0;
        atomicAdd(&counts[i0], 1);
        atomicAdd(&counts[i1], 1);
    }
}

__global__ void scan_kernel(const int* __restrict__ counts,
                            int* __restrict__ offs, int* __restrict__ cursors) {
    if (threadIdx.x == 0) {
        int a = 0;
        for (int e = 0; e < NEXP; e++) { offs[e] = a; cursors[e] = a; a += counts[e]; }
    }
}

// fill_kernel: also records slots[2t+k] = position of (t,k) in the permuted
// order, so the routed-down result can be gathered WITHOUT atomics.
__global__ void fill_kernel(const int* __restrict__ topi, const float* __restrict__ topw,
                            int* __restrict__ cursors,
                            int* __restrict__ rowlist, float* __restrict__ wlist,
                            int* __restrict__ slots) {
    int t = blockIdx.x * 256 + threadIdx.x;   // 0..8191
#pragma unroll
    for (int k = 0; k < 2; k++) {
        int e = topi[2 * t + k];
        int pos = atomicAdd(&cursors[e], 1);
        rowlist[pos] = t;
        wlist[pos] = topw[2 * t + k];
        slots[2 * t + k] = pos;
    }
}

// combine: out[t] += yr[slot0(t)] + yr[slot1(t)]  (weights pre-applied in MODE 3)
// one block (256 thr * float4 = 1024 cols) per token
__global__ __launch_bounds__(256) void combine_kernel(
    const int* __restrict__ slots, const float* __restrict__ yr,
    float* __restrict__ out) {
    int t = blockIdx.x;
    int p0 = slots[2 * t], p1 = slots[2 * t + 1];
    int i = threadIdx.x;
    const float4* a = (const float4*)(yr + (size_t)p0 * DMODEL);
    const float4* b = (const float4*)(yr + (size_t)p1 * DMODEL);
    float4* o = (float4*)(out + (size_t)t * DMODEL);
    float4 va = a[i], vb = b[i], vo = o[i];
    vo.x += va.x + vb.x;
    vo.y += va.y + vb.y;
    vo.z += va.z + vb.z;
    vo.w += va.w + vb.w;
    o[i] = vo;
}

// ---------------------------------------------------------------------------
// bf16 GEMM, C = A(MxK) * Bt(NxK)^T  — 128x128 tile, BK=64, 4 waves 2x2,
// 16x16x32 MFMA, global_load_lds width-16 staging, single-buffer serial
// k-loop (proven best at 4 blocks/CU; dbuf variant measured WORSE, R4).
// T1 XCD swizzle: HW assigns XCD = linear_wgid % 8, so consecutive x-blocks
// (which share the same B-panel by) scatter across all 8 non-coherent L2s,
// each refilling the panel (R5 FETCH = 3.4x ideal).  Bijective remap
// swz = (lin%8)*(nwg/8) + lin/8 gives each XCD a contiguous swz chunk ->
// a FIXED subset of by panels (4 at gy=32, 1 at gy=8): every B-panel is
// L2-filled once instead of 8 times.  nwg (2048 / 512) % 8 == 0 always.
// LDS layout is XOR-swizzled: row r's k-chunk kc (8 elems, 16B) lives at
// byte offset r*128 + ((kc ^ (r&7))<<4).
// MODE 0: shared up:   A=xnb dense, epi gelu(v+sb1) -> hs bf16
// MODE 1: shared down: A=hs dense,  epi out = x + v + sb2 (fp32)
// MODE 2: routed up:   A=xnb gathered via rowlist, epi gelu(v+b1[e]) -> hr bf16
// MODE 3: routed down: A=hr dense-in-segment, epi yr[pos] = w*(v+b2[e]) (fp32,
//         dense coalesced store, NO atomics — combine_kernel scatters later)
// ---------------------------------------------------------------------------
template <int MODE>
__global__ __launch_bounds__(256, 4) void gemm_bt(
    const __hip_bfloat16* __restrict__ A,
    const __hip_bfloat16* __restrict__ Bt,
    const float* __restrict__ bias,
    const float* __restrict__ xres,
    float* __restrict__ outf,
    __hip_bfloat16* __restrict__ outb,
    const int* __restrict__ rowlist,
    const float* __restrict__ wlist,
    const int* __restrict__ offs,
    const int* __restrict__ counts,
    int K, int N) {
    // ---- T1 XCD-aware tile remap (pure permutation of (bx,by) per z) ----
    int gx = gridDim.x, gy = gridDim.y;
    int lin = blockIdx.x + gx * blockIdx.y;
    int nwg = gx * gy;                       // 2048 or 512, both %8==0
    int swz = (lin & 7) * (nwg >> 3) + (lin >> 3);
    int bx = swz % gx, by = swz / gx;

    int e = 0, seg_off = 0, Mcnt = 0;
    if constexpr (MODE >= 2) {
        e = blockIdx.z;
        Mcnt = counts[e];
        if (bx * 128 >= Mcnt) return;        // ragged early-exit (block-uniform)
        seg_off = offs[e];
    }
    const __hip_bfloat16* Bte = Bt + (size_t)e * (size_t)N * K;
    const float* biase = bias + (size_t)e * N;
    int row0 = bx * 128, col0 = by * 128;

    __shared__ __align__(16) __hip_bfloat16 sA[128 * 64];
    __shared__ __align__(16) __hip_bfloat16 sB[128 * 64];

    int tid = threadIdx.x, wave = tid >> 6, lane = tid & 63;
    int wm = wave >> 1, wn = wave & 1;

    // staging pointers: chunk c = wave*4+i covers 8 rows (A) / 8 n-rows (B);
    // lane L -> row c*8 + L/8, k-chunk (L%8) ^ (L/8)  [XOR swizzle]
    int kc = ((lane & 7) ^ (lane >> 3)) * 8;   // swizzled k-element offset
    const __hip_bfloat16* aptr[4];
    const __hip_bfloat16* bptr[4];
#pragma unroll
    for (int i = 0; i < 4; i++) {
        int c = wave * 4 + i;
        int rr = c * 8 + (lane >> 3);
        size_t arow;
        if constexpr (MODE == 0 || MODE == 1) {
            arow = (size_t)(row0 + rr);
        } else {
            int p = row0 + rr; if (p > Mcnt - 1) p = Mcnt - 1;   // clamp ragged tail
            arow = (MODE == 2) ? (size_t)rowlist[seg_off + p] : (size_t)(seg_off + p);
        }
        aptr[i] = A + arow * K + kc;
        int nn = col0 + c * 8 + (lane >> 3);
        bptr[i] = Bte + (size_t)nn * K + kc;
    }

    f32x4 acc[4][4];
#pragma unroll
    for (int tm = 0; tm < 4; tm++)
#pragma unroll
        for (int tn = 0; tn < 4; tn++) acc[tm][tn] = (f32x4){0.f, 0.f, 0.f, 0.f};

    char* sAc = (char*)&sA[0];
    char* sBc = (char*)&sB[0];

    for (int k0 = 0; k0 < K; k0 += 64) {
#pragma unroll
        for (int i = 0; i < 4; i++) {
            int c = wave * 4 + i;
            async_copy16(aptr[i], sAc + c * 1024);
            async_copy16(bptr[i], sBc + c * 1024);
            aptr[i] += 64;
            bptr[i] += 64;
        }
        asm volatile("s_waitcnt vmcnt(0)" ::: "memory");
        __syncthreads();
        const short* sa = (const short*)sAc;
        const short* sb = (const short*)sBc;
#pragma unroll
        for (int kk = 0; kk < 64; kk += 32) {
            // k-chunk index for this lane-half, then XOR with row&7 (== lane&7
            // for all fragment rows, since fragment row = multiple-of-16 + (lane&15))
            int kbc = (kk >> 3) + (lane >> 4);
            int swzk = ((kbc ^ (lane & 7)) << 3);   // short offset within row
            bf16x8 af[4], bfr[4];
#pragma unroll
            for (int tm = 0; tm < 4; tm++)
                af[tm] = *(const bf16x8*)(sa + (size_t)(wm * 64 + tm * 16 + (lane & 15)) * 64 + swzk);
#pragma unroll
            for (int tn = 0; tn < 4; tn++)
                bfr[tn] = *(const bf16x8*)(sb + (size_t)(wn * 64 + tn * 16 + (lane & 15)) * 64 + swzk);
#pragma unroll
            for (int tm = 0; tm < 4; tm++)
#pragma unroll
                for (int tn = 0; tn < 4; tn++)
                    acc[tm][tn] = __builtin_amdgcn_mfma_f32_16x16x32_bf16(
                        af[tm], bfr[tn], acc[tm][tn], 0, 0, 0);
        }
        __syncthreads();
    }

    // epilogue — C/D layout: col = lane&15, row = (lane>>4)*4 + i
#pragma unroll
    for (int tm = 0; tm < 4; tm++) {
        int rbase = wm * 64 + tm * 16 + ((lane >> 4) << 2);
        float wv[4];
        if constexpr (MODE == 3) {
#pragma unroll
            for (int i = 0; i < 4; i++) {
                int p = row0 + rbase + i;
                wv[i] = (p < Mcnt) ? wlist[seg_off + p] : 0.0f;
            }
        }
#pragma unroll
        for (int tn = 0; tn < 4; tn++) {
            int c = col0 + wn * 64 + tn * 16 + (lane & 15);
            float bb = biase[c];
#pragma unroll
            for (int i = 0; i < 4; i++) {
                int rl = rbase + i;
                float v = acc[tm][tn][i] + bb;
                if constexpr (MODE == 0) {
                    outb[(size_t)(row0 + rl) * N + c] = __float2bfloat16(gelu_tanh(v));
                } else if constexpr (MODE == 1) {
                    size_t idx = (size_t)(row0 + rl) * N + c;
                    outf[idx] = xres[idx] + v;
                } else if constexpr (MODE == 2) {
                    int p = row0 + rl;
                    if (p < Mcnt)
                        outb[(size_t)(seg_off + p) * N + c] = __float2bfloat16(gelu_tanh(v));
                } else {
                    int p = row0 + rl;
                    if (p < Mcnt)
                        outf[(size_t)(seg_off + p) * N + c] = wv[i] * v;
                }
            }
        }
    }
}

// ---------------------------------------------------------------------------
// Launch order is chosen for L3 producer->consumer adjacency (R5: -140 us):
// each weight transpose runs IMMEDIATELY before the GEMM that consumes it,
// keeping the B-operand L3-resident at read time.
// ---------------------------------------------------------------------------
extern "C" void kernel_launch(void* const* d_in, const int* in_sizes, int n_in,
                              void* d_out, int out_size, void* d_ws, size_t ws_size,
                              hipStream_t stream) {
    const float* x      = (const float*)d_in[0];
    const float* time_c = (const float*)d_in[1];
    const float* ada_w  = (const float*)d_in[2];
    const float* ada_b  = (const float*)d_in[3];
    const float* gate_w = (const float*)d_in[4];
    const float* w1     = (const float*)d_in[5];
    const float* b1     = (const float*)d_in[6];
    const float* w2     = (const float*)d_in[7];
    const float* b2     = (const float*)d_in[8];
    const float* sw1    = (const float*)d_in[9];
    const float* sb1    = (const float*)d_in[10];
    const float* sw2    = (const float*)d_in[11];
    const float* sb2    = (const float*)d_in[12];
    float* out = (float*)d_out;
    (void)in_sizes; (void)n_in; (void)out_size; (void)ws_size;

    char* ws = (char*)d_ws;
    size_t off = 0;
    auto alloc = [&](size_t bytes) -> char* {
        char* p = ws + off;
        off += (bytes + 255) & ~(size_t)255;
        return p;
    };
    __hip_bfloat16* xnb  = (__hip_bfloat16*)alloc((size_t)T_TOKENS * DMODEL * 2);
    __hip_bfloat16* w1t  = (__hip_bfloat16*)alloc((size_t)NEXP * DMODEL * DHID * 2);
    __hip_bfloat16* w2t  = (__hip_bfloat16*)alloc((size_t)NEXP * DMODEL * DHID * 2);
    __hip_bfloat16* sw1t = (__hip_bfloat16*)alloc((size_t)DMODEL * DHID * 2);
    __hip_bfloat16* sw2t = (__hip_bfloat16*)alloc((size_t)DMODEL * DHID * 2);
    __hip_bfloat16* hs   = (__hip_bfloat16*)alloc((size_t)T_TOKENS * DHID * 2);
    __hip_bfloat16* hr   = (__hip_bfloat16*)alloc((size_t)2 * T_TOKENS * DHID * 2);
    float* cond    = (float*)alloc(4 * 2048 * 4);
    int*   topi    = (int*)alloc(T_TOKENS * 2 * 4);
    float* topw    = (float*)alloc(T_TOKENS * 2 * 4);
    int*   rowlist = (int*)alloc(2 * T_TOKENS * 4);
    float* wlist   = (float*)alloc(2 * T_TOKENS * 4);
    int*   slots   = (int*)alloc(2 * T_TOKENS * 4);
    int*   counts  = (int*)alloc(256);
    int*   offs    = (int*)alloc(256);
    int*   cursors = (int*)alloc(256);
    // yr (routed-down weighted contributions, fp32, 2T x D = 67.1 MB) aliases
    // hs (8192 x 4096 bf16 = 67.1 MB): hs is dead after gemm_bt<1>, and stream
    // ordering guarantees gemm_bt<1> completes before gemm_bt<3> writes yr.
    float* yr = (float*)hs;

    hipMemsetAsync(counts, 0, NEXP * sizeof(int), stream);

    dim3 tb(32, 8);

    // --- routing + normalization first (xnb / rowlist ready for all GEMMs) ---
    cond_kernel<<<32, 256, 0, stream>>>(time_c, ada_w, ada_b, cond);
    ln_gate_kernel<<<T_TOKENS, 256, 0, stream>>>(x, cond, gate_w, xnb, topi, topw, counts);
    scan_kernel<<<1, 64, 0, stream>>>(counts, offs, cursors);
    fill_kernel<<<32, 256, 0, stream>>>(topi, topw, cursors, rowlist, wlist, slots);

    // --- shared expert: transpose each weight right before its GEMM ---
    transpose_cvt<<<dim3(128, 32, 1), tb, 0, stream>>>(sw1, sw1t, 1024, 4096);
    gemm_bt<0><<<dim3(64, 32), 256, 0, stream>>>(xnb, sw1t, sb1, nullptr, nullptr, hs,
                                                 nullptr, nullptr, nullptr, nullptr, 1024, 4096);
    transpose_cvt<<<dim3(32, 128, 1), tb, 0, stream>>>(sw2, sw2t, 4096, 1024);
    gemm_bt<1><<<dim3(64, 8), 256, 0, stream>>>(hs, sw2t, sb2, x, out, nullptr,
                                                nullptr, nullptr, nullptr, nullptr, 4096, 1024);

    // --- routed experts: w1t hot for MODE2, w2t hot for MODE3 ---
    transpose_cvt<<<dim3(128, 32, 8), tb, 0, stream>>>(w1, w1t, 1024, 4096);
    gemm_bt<2><<<dim3(64, 32, 8), 256, 0, stream>>>(xnb, w1t, b1, nullptr, nullptr, hr,
                                                    rowlist, nullptr, offs, counts, 1024, 4096);
    transpose_cvt<<<dim3(32, 128, 8), tb, 0, stream>>>(w2, w2t, 4096, 1024);
    gemm_bt<3><<<dim3(64, 8, 8), 256, 0, stream>>>(hr, w2t, b2, nullptr, yr, nullptr,
                                                   nullptr, wlist, offs, counts, 4096, 1024);
    combine_kernel<<<T_TOKENS, 256, 0, stream>>>(slots, yr, out);
}